// Round 3
// baseline (217.367 us; speedup 1.0000x reference)
//
#include <hip/hip_runtime.h>
#include <math.h>

#define BB 4
#define SS 4096
#define DD 1024
#define HH 16
#define GG 4
#define KK 3
#define DG 256
#define DH 64
#define CH 32            // s-rows per k_main block
#define NCH (SS / CH)    // 128 chunks per batch

// ---- workspace layout (float offsets, all float4-aligned) ----
enum : size_t {
  OFF_WEFF  = 0,        // 768 (pad 1024)
  OFF_OFFC  = 1024,     // 4 (pad 256)
  OFF_WEQ   = 1280,     // 12*DD = 12288   [j=g*3+k][c]
  OFF_WX    = 13568,    // B*G*S = 65536   [b][g][s]
  OFF_XWP   = 79104,    // B*5*NCH*DD = 2621440 partials [b][slot][chunk][c]
  OFF_XW    = 2700544,  // B*G*D = 16384   [b][g][c]
  OFF_XS    = 2716928,  // B*D = 4096
  OFF_SW    = 2721024,  // B*G = 16 (pad 256)
  OFF_FEAT  = 2721280,  // B*D = 4096
  OFF_KF    = 2725376,  // B*G*D = 16384   [b][g][o]
  OFF_VF    = 2741760,  // B*G*D = 16384
  OFF_QW    = 2758144,  // B*D*G = 16384   [b][I][g]
  OFF_QS    = 2774528,  // B*D = 4096
  OFF_AV    = 2778624,  // B*D*G = 16384   [b][d][g]
  OFF_AB    = 2795008,  // B*D = 4096
  OFF_C2    = 2799104,  // B*D = 4096
  OFF_WAV   = 2803200,  // B*D*G = 16384   [b][o][g]
  OFF_WOSUM = 2819584,  // D = 1024
  WS_FLOATS = 2820608   // ~11.3 MB
};

__device__ __forceinline__ float wred_sum(float v) {
#pragma unroll
  for (int o = 32; o > 0; o >>= 1) v += __shfl_xor(v, o, 64);
  return v;
}
__device__ __forceinline__ float wred_max(float v) {
#pragma unroll
  for (int o = 32; o > 0; o >>= 1) v = fmaxf(v, __shfl_xor(v, o, 64));
  return v;
}

// ---- P1: Weff (wave/output), feat, WoSum ----
// blocks [0,192): Weff   [192,208): feat   [208,464): WoSum
__global__ void k_pre1(const float* __restrict__ Woff1, const float* __restrict__ Woff2,
                       const float* __restrict__ x, const float* __restrict__ Wo,
                       float* __restrict__ ws) {
  const int t = threadIdx.x;
  const int lane = t & 63;
  if (blockIdx.x < 192) {                        // Weff[i][kk], one wave per output
    const int widx = (blockIdx.x * 256 + t) >> 6;   // 0..767
    const int i = widx / 3, kk = widx - 3 * i;
    float a = 0.f;
#pragma unroll
    for (int u = 0; u < 4; ++u) {
      const int cc = lane + 64 * u;
      a += Woff2[cc] * Woff1[(size_t)(cc * DG + i) * KK + kk];
    }
    a = wred_sum(a);
    if (lane == 0) ws[OFF_WEFF + widx] = a;
  } else if (blockIdx.x < 208) {                 // feat[b][c]
    const int gid = (blockIdx.x - 192) * 256 + t;  // 0..4095
    const int b = gid >> 10, c = gid & 1023;
    ws[OFF_FEAT + gid] = 0.5f * (x[((size_t)b * SS + 2047) * DD + c] +
                                 x[((size_t)b * SS + 2048) * DD + c]);
  } else {                                       // WoSum[o], wave per output
    const int o = ((blockIdx.x - 208) * 256 + t) >> 6;  // 0..1023
    const float4* wo = (const float4*)(Wo + (size_t)o * DD);
    float v = 0.f;
#pragma unroll
    for (int it = 0; it < 4; ++it) {
      const float4 a = wo[lane + 64 * it];
      v += a.x + a.y + a.z + a.w;
    }
    v = wred_sum(v);
    if (lane == 0) ws[OFF_WOSUM + o] = v;
  }
}

// ---- P2: Weq (192 wide blocks, 4-way i-split) + offc (block 192) ----
__global__ void k_pre2(const float* __restrict__ Wq, const float* __restrict__ bq,
                       const float* __restrict__ Woff2, const float* __restrict__ boff1,
                       float* __restrict__ ws) {
  const float* Weff = ws + OFF_WEFF;
  const int t = threadIdx.x;
  const int lane = t & 63;
  if (blockIdx.x < 192) {
    const int j = blockIdx.x >> 4;               // 0..11
    const int c0 = (blockIdx.x & 15) * 64;
    const int g = j / 3, kk = j - 3 * g;
    const int q = t >> 6;
    float a = 0.f;
#pragma unroll 4
    for (int ii = 0; ii < 64; ++ii) {
      const int i = q * 64 + ii;
      a += Weff[i * KK + kk] * Wq[(size_t)(g * DG + i) * DD + c0 + lane];
    }
    __shared__ float red[4][64];
    red[q][lane] = a;
    __syncthreads();
    if (q == 0) {
      const float v = red[0][lane] + red[1][lane] + red[2][lane] + red[3][lane];
      ws[OFF_WEQ + (size_t)j * DD + c0 + lane] = v;
    }
  } else {                                       // offc[g] on wave 0
    if (t >= 64) return;
    float beff = 0.f;
#pragma unroll
    for (int u = 0; u < 4; ++u) {
      const int cc = lane + 64 * u;
      beff += Woff2[cc] * boff1[cc];
    }
    beff = wred_sum(beff);
#pragma unroll
    for (int g = 0; g < 4; ++g) {
      float a = 0.f;
#pragma unroll
      for (int u = 0; u < 4; ++u) {
        const int i = lane + 64 * u;
        a += (Weff[i * 3 + 0] + Weff[i * 3 + 1] + Weff[i * 3 + 2]) * bq[g * DG + i];
      }
      a = wred_sum(a);
      if (lane == 0) ws[OFF_OFFC + g] = a + beff;
    }
  }
}

// ---- MAIN: fused z -> wx -> weighted partial sums. Block = (b, 32-row chunk). ----
// Phase 1: z rows [s0-1, s0+32] (halo), wave-per-row, Weq in 192 VGPRs.
// Phase 2: wx for the 32 rows (threads 0..31).
// Phase 3: re-read the tile (L2-hot) and accumulate Xw/Xs partials.
__global__ __launch_bounds__(256, 2) void k_main(const float* __restrict__ x,
                                                 float* __restrict__ ws) {
  const int b = blockIdx.x >> 7;
  const int chunk = blockIdx.x & 127;
  const int s0 = chunk * CH;
  const int t = threadIdx.x;
  const int lane = t & 63;
  const int wvid = t >> 6;
  __shared__ float zsh[CH + 2][12];
  __shared__ float wxs[4][CH];

  const float* weq = ws + OFF_WEQ;
  float4 w[12][4];
#pragma unroll
  for (int j = 0; j < 12; ++j)
#pragma unroll
    for (int it = 0; it < 4; ++it)
      w[j][it] = *(const float4*)(weq + (size_t)j * DD + 4 * (lane + 64 * it));

  for (int r = wvid; r < CH + 2; r += 4) {
    const int s = s0 - 1 + r;
    if (s < 0 || s >= SS) continue;
    const float4* xr = (const float4*)(x + (size_t)(b * SS + s) * DD);
    float4 xv[4];
#pragma unroll
    for (int it = 0; it < 4; ++it) xv[it] = xr[lane + 64 * it];
    float acc[12];
#pragma unroll
    for (int j = 0; j < 12; ++j) {
      float a = 0.f;
#pragma unroll
      for (int it = 0; it < 4; ++it)
        a += xv[it].x * w[j][it].x + xv[it].y * w[j][it].y +
             xv[it].z * w[j][it].z + xv[it].w * w[j][it].w;
      acc[j] = a;
    }
#pragma unroll
    for (int j = 0; j < 12; ++j) acc[j] = wred_sum(acc[j]);
    if (lane == 0) {
#pragma unroll
      for (int j = 0; j < 12; ++j) zsh[r][j] = acc[j];
    }
  }
  __syncthreads();

  if (t < CH) {
    const int s = s0 + t;
#pragma unroll
    for (int g = 0; g < 4; ++g) {
      float off = ws[OFF_OFFC + g];
      if (s > 0)      off += zsh[t][g * 3 + 0];
      off += zsh[t + 1][g * 3 + 1];
      if (s < SS - 1) off += zsh[t + 2][g * 3 + 2];
      off = tanhf(off) * (float)KK;
      const float vg = 2.0f * ((float)s + off) / (float)(SS - 1) - 1.0f;
      float wvv = 1.0f - fabsf(0.5f * vg);
      wvv = fminf(fmaxf(wvv, 0.0f), 1.0f);
      wxs[g][t] = wvv;
      ws[OFF_WX + (size_t)(b * GG + g) * SS + s] = wvv;
    }
  }
  __syncthreads();

  float4 aw[5] = {};
#pragma unroll 4
  for (int si = 0; si < CH; ++si) {
    const int s = s0 + si;
    const float4 f = *(const float4*)(x + (size_t)(b * SS + s) * DD + 4 * t);
    const float w0 = wxs[0][si], w1 = wxs[1][si], w2 = wxs[2][si], w3 = wxs[3][si];
    aw[0].x += f.x * w0; aw[0].y += f.y * w0; aw[0].z += f.z * w0; aw[0].w += f.w * w0;
    aw[1].x += f.x * w1; aw[1].y += f.y * w1; aw[1].z += f.z * w1; aw[1].w += f.w * w1;
    aw[2].x += f.x * w2; aw[2].y += f.y * w2; aw[2].z += f.z * w2; aw[2].w += f.w * w2;
    aw[3].x += f.x * w3; aw[3].y += f.y * w3; aw[3].z += f.z * w3; aw[3].w += f.w * w3;
    aw[4].x += f.x; aw[4].y += f.y; aw[4].z += f.z; aw[4].w += f.w;
  }
#pragma unroll
  for (int slot = 0; slot < 5; ++slot)
    *(float4*)(ws + OFF_XWP + (((size_t)(b * 5 + slot) * NCH + chunk) * DD) + 4 * t) = aw[slot];
}

// ---- reduce partials; blocks [0,320): Xw/Xs  [320,336): Sw ----
__global__ void k_xw_red(float* __restrict__ ws) {
  const int t = threadIdx.x;
  const int lane = t & 63;
  if (blockIdx.x < 320) {
    const int b = blockIdx.x / 80;
    const int rem = blockIdx.x - b * 80;
    const int slot = rem >> 4;
    const int c0 = (rem & 15) * 64;
    const int q = t >> 6;
    const float* base = ws + OFF_XWP + (size_t)(b * 5 + slot) * NCH * DD;
    float a = 0.f;
#pragma unroll 4
    for (int ii = 0; ii < 32; ++ii) {
      const int ch = q * 32 + ii;
      a += base[(size_t)ch * DD + c0 + lane];
    }
    __shared__ float red[4][64];
    red[q][lane] = a;
    __syncthreads();
    if (q == 0) {
      const float v = red[0][lane] + red[1][lane] + red[2][lane] + red[3][lane];
      if (slot < 4) ws[OFF_XW + ((size_t)(b * GG + slot)) * DD + c0 + lane] = v;
      else          ws[OFF_XS + (size_t)b * DD + c0 + lane] = v;
    }
  } else {                                       // Sw[b*4+g]
    const int w = blockIdx.x - 320;              // 0..15
    const float* wx = ws + OFF_WX + (size_t)w * SS;
    float a = 0.f;
#pragma unroll 4
    for (int it = 0; it < 16; ++it) a += wx[t + 256 * it];
    a = wred_sum(a);
    __shared__ float red[4];
    if (lane == 0) red[t >> 6] = a;
    __syncthreads();
    if (t == 0) ws[OFF_SW + w] = red[0] + red[1] + red[2] + red[3];
  }
}

// ---- dots: blocks [0,1024): wave per (g,o) -> Kf,Vf all b
//            blocks [1024,2048): wave per (b,I) -> Qw all g + Qs ----
__global__ void k_dots(const float* __restrict__ Wq, const float* __restrict__ bq,
                       const float* __restrict__ Wk, const float* __restrict__ Wv,
                       float* __restrict__ ws) {
  const int t = threadIdx.x;
  const int lane = t & 63;
  if (blockIdx.x < 1024) {
    const int widx = blockIdx.x * 4 + (t >> 6);  // 0..4095
    const int g = widx >> 10, o = widx & 1023;
    const float4 ak = ((const float4*)(Wk + (size_t)o * DD + g * DG))[lane];
    const float4 avv = ((const float4*)(Wv + (size_t)o * DD + g * DG))[lane];
    float kk[4], vv[4];
#pragma unroll
    for (int b = 0; b < 4; ++b) {
      const float4 f = ((const float4*)(ws + OFF_FEAT + (size_t)b * DD + g * DG))[lane];
      kk[b] = ak.x * f.x + ak.y * f.y + ak.z * f.z + ak.w * f.w;
      vv[b] = avv.x * f.x + avv.y * f.y + avv.z * f.z + avv.w * f.w;
    }
#pragma unroll
    for (int b = 0; b < 4; ++b) { kk[b] = wred_sum(kk[b]); vv[b] = wred_sum(vv[b]); }
    if (lane == 0) {
#pragma unroll
      for (int b = 0; b < 4; ++b) {
        ws[OFF_KF + ((size_t)(b * GG + g)) * DD + o] = kk[b];
        ws[OFF_VF + ((size_t)(b * GG + g)) * DD + o] = vv[b];
      }
    }
  } else {
    const int widx = (blockIdx.x - 1024) * 4 + (t >> 6);  // 0..4095
    const int b = widx >> 10, I = widx & 1023;
    const float4* wq = (const float4*)(Wq + (size_t)I * DD);
    float4 a[4];
#pragma unroll
    for (int it = 0; it < 4; ++it) a[it] = wq[lane + 64 * it];
    float acc[5] = {0.f, 0.f, 0.f, 0.f, 0.f};
#pragma unroll
    for (int g = 0; g < 4; ++g) {
      const float4* xw = (const float4*)(ws + OFF_XW + (size_t)(b * GG + g) * DD);
#pragma unroll
      for (int it = 0; it < 4; ++it) {
        const float4 c = xw[lane + 64 * it];
        acc[g] += a[it].x * c.x + a[it].y * c.y + a[it].z * c.z + a[it].w * c.w;
      }
    }
    const float4* xs = (const float4*)(ws + OFF_XS + (size_t)b * DD);
#pragma unroll
    for (int it = 0; it < 4; ++it) {
      const float4 c = xs[lane + 64 * it];
      acc[4] += a[it].x * c.x + a[it].y * c.y + a[it].z * c.z + a[it].w * c.w;
    }
#pragma unroll
    for (int u = 0; u < 5; ++u) acc[u] = wred_sum(acc[u]);
    if (lane == 0) {
      const float bqi = bq[I];
#pragma unroll
      for (int g = 0; g < 4; ++g)
        ws[OFF_QW + ((size_t)(b * DD + I)) * 4 + g] = acc[g] + bqi * ws[OFF_SW + b * GG + g];
      ws[OFF_QS + (size_t)b * DD + I] = acc[4] + (float)SS * bqi;
    }
  }
}

// ---- attn: scores -> softmax -> AV, Ab. One wave per (b, d) row; lane = j ----
__global__ void k_attn(const float* __restrict__ bk, const float* __restrict__ bv,
                       float* __restrict__ ws) {
  const int gid = blockIdx.x * blockDim.x + threadIdx.x;
  const int lane = gid & 63;
  const int w = gid >> 6;                        // w = b*1024 + d
  if (w >= BB * DD) return;
  const int b = w >> 10, d = w & 1023;
  const int hh = d >> 6;
  const int J = (hh << 6) | lane;
  const float* Qw = ws + OFF_QW + (size_t)w * 4;
  const float q0 = Qw[0], q1 = Qw[1], q2 = Qw[2], q3 = Qw[3];
  const float qs = ws[OFF_QS + w];
  const float* Kf = ws + OFF_KF + (size_t)b * GG * DD;
  float sc = q0 * Kf[0 * DD + J] + q1 * Kf[1 * DD + J] +
             q2 * Kf[2 * DD + J] + q3 * Kf[3 * DD + J] + bk[J] * qs;
  sc *= 0.03125f;                                // D^-0.5 = 1/32
  const float m = wred_max(sc);
  const float e = expf(sc - m);
  const float sum = wred_sum(e);
  const float attn = e / sum;
  const float* Vf = ws + OFF_VF + (size_t)b * GG * DD;
#pragma unroll
  for (int g = 0; g < 4; ++g) {
    const float av = wred_sum(attn * Vf[(size_t)g * DD + J]);
    if (lane == 0) ws[OFF_AV + (size_t)w * 4 + g] = av;
  }
  const float ab = wred_sum(attn * bv[J]);
  if (lane == 0) ws[OFF_AB + w] = ab;
}

// ---- WAV[b,o,g] = sum_d Wo[o,d]*AV[b,d,g]; C2 = sum_d Wo*Ab + bo ----
__global__ void k_wav(const float* __restrict__ Wo, const float* __restrict__ bo,
                      float* __restrict__ ws) {
  const int gid = blockIdx.x * blockDim.x + threadIdx.x;
  const int lane = gid & 63;
  const int w = gid >> 6;                        // w = b*1024 + o
  if (w >= BB * DD) return;
  const int b = w >> 10, o = w & 1023;
  float acc0 = 0, acc1 = 0, acc2 = 0, acc3 = 0, acc4 = 0;
  const float4* wo4 = (const float4*)(Wo + (size_t)o * DD);
  const float* AV = ws + OFF_AV + (size_t)b * DD * 4;
  const float* Ab = ws + OFF_AB + (size_t)b * DD;
#pragma unroll
  for (int it = 0; it < 4; ++it) {
    const int d4 = lane + 64 * it;               // d = 4*d4 .. 4*d4+3
    const float4 wv = wo4[d4];
    const float4 a0 = *(const float4*)(AV + (size_t)(4 * d4 + 0) * 4);
    const float4 a1 = *(const float4*)(AV + (size_t)(4 * d4 + 1) * 4);
    const float4 a2 = *(const float4*)(AV + (size_t)(4 * d4 + 2) * 4);
    const float4 a3 = *(const float4*)(AV + (size_t)(4 * d4 + 3) * 4);
    acc0 += wv.x * a0.x + wv.y * a1.x + wv.z * a2.x + wv.w * a3.x;
    acc1 += wv.x * a0.y + wv.y * a1.y + wv.z * a2.y + wv.w * a3.y;
    acc2 += wv.x * a0.z + wv.y * a1.z + wv.z * a2.z + wv.w * a3.z;
    acc3 += wv.x * a0.w + wv.y * a1.w + wv.z * a2.w + wv.w * a3.w;
    const float4 abv = *(const float4*)(Ab + 4 * d4);
    acc4 += wv.x * abv.x + wv.y * abv.y + wv.z * abv.z + wv.w * abv.w;
  }
  acc0 = wred_sum(acc0); acc1 = wred_sum(acc1); acc2 = wred_sum(acc2);
  acc3 = wred_sum(acc3); acc4 = wred_sum(acc4);
  if (lane == 0) {
    float* WAV = ws + OFF_WAV + (size_t)w * 4;
    WAV[0] = acc0; WAV[1] = acc1; WAV[2] = acc2; WAV[3] = acc3;
    ws[OFF_C2 + w] = acc4 + bo[o];
  }
}

// ---- out[b,s,o] = sum_g wx*WAV + C2 + bias_table[s]*WoSum (16-s chunks) ----
__global__ __launch_bounds__(256) void k_out(const float* __restrict__ btab,
                                             const float* __restrict__ ws,
                                             float* __restrict__ out) {
  const int b = blockIdx.x >> 8;
  const int ch = blockIdx.x & 255;
  const int t = threadIdx.x;
  const int o0 = 4 * t;
  float4 wav[4];
#pragma unroll
  for (int io = 0; io < 4; ++io)
    wav[io] = *(const float4*)(ws + OFF_WAV + (size_t)(b * DD + o0 + io) * 4);
  const float4 c24 = *(const float4*)(ws + OFF_C2 + (size_t)b * DD + o0);
  const float4 wos4 = *(const float4*)(ws + OFF_WOSUM + o0);
  const float* wx = ws + OFF_WX;
  const int s0 = ch * 16;
#pragma unroll 2
  for (int si = 0; si < 16; ++si) {
    const int s = s0 + si;
    const float w0 = wx[(size_t)(b * GG + 0) * SS + s];
    const float w1 = wx[(size_t)(b * GG + 1) * SS + s];
    const float w2 = wx[(size_t)(b * GG + 2) * SS + s];
    const float w3 = wx[(size_t)(b * GG + 3) * SS + s];
    const float bt = btab[s];
    float4 val;
    val.x = c24.x + bt * wos4.x + w0 * wav[0].x + w1 * wav[0].y + w2 * wav[0].z + w3 * wav[0].w;
    val.y = c24.y + bt * wos4.y + w0 * wav[1].x + w1 * wav[1].y + w2 * wav[1].z + w3 * wav[1].w;
    val.z = c24.z + bt * wos4.z + w0 * wav[2].x + w1 * wav[2].y + w2 * wav[2].z + w3 * wav[2].w;
    val.w = c24.w + bt * wos4.w + w0 * wav[3].x + w1 * wav[3].y + w2 * wav[3].z + w3 * wav[3].w;
    *(float4*)(out + (size_t)(b * SS + s) * DD + o0) = val;
  }
}

extern "C" void kernel_launch(void* const* d_in, const int* in_sizes, int n_in,
                              void* d_out, int out_size, void* d_ws, size_t ws_size,
                              hipStream_t stream) {
  const float* x     = (const float*)d_in[0];
  const float* Wq    = (const float*)d_in[1];
  const float* bq    = (const float*)d_in[2];
  const float* Wk    = (const float*)d_in[3];
  const float* bk    = (const float*)d_in[4];
  const float* Wv    = (const float*)d_in[5];
  const float* bv    = (const float*)d_in[6];
  const float* Wo    = (const float*)d_in[7];
  const float* bo    = (const float*)d_in[8];
  const float* Woff1 = (const float*)d_in[9];
  const float* boff1 = (const float*)d_in[10];
  const float* Woff2 = (const float*)d_in[11];
  const float* btab  = (const float*)d_in[12];
  float* ws  = (float*)d_ws;
  float* out = (float*)d_out;

  k_pre1<<<464, 256, 0, stream>>>(Woff1, Woff2, x, Wo, ws);
  k_pre2<<<193, 256, 0, stream>>>(Wq, bq, Woff2, boff1, ws);
  k_main<<<512, 256, 0, stream>>>(x, ws);
  k_xw_red<<<336, 256, 0, stream>>>(ws);
  k_dots<<<2048, 256, 0, stream>>>(Wq, bq, Wk, Wv, ws);
  k_attn<<<1024, 256, 0, stream>>>(bk, bv, ws);
  k_wav<<<1024, 256, 0, stream>>>(Wo, bo, ws);
  k_out<<<1024, 256, 0, stream>>>(btab, ws, out);
}

// Round 5
// 215.121 us; speedup vs baseline: 1.0104x; 1.0104x over previous
//
#include <hip/hip_runtime.h>
#include <math.h>

#define BB 4
#define SS 4096
#define DD 1024
#define HH 16
#define GG 4
#define KK 3
#define DG 256
#define DH 64
#define CH 16            // s-rows per k_xw / k_out block
#define NCH (SS / CH)    // 256 chunks per batch

// ---- workspace layout (float offsets, all float4-aligned) ----
enum : size_t {
  OFF_WEFF  = 0,        // 768 (pad 1024)
  OFF_OFFC  = 1024,     // 4 (pad 256)
  OFF_WEQ   = 1280,     // 12*DD = 12288
  OFF_ZT    = 13568,    // B*S*12 = 196608 [b][s][j]
  OFF_WX    = 210176,   // B*G*S = 65536
  OFF_XWP   = 275712,   // B*5*NCH*DD = 5242880 [b][slot][chunk][c]
  OFF_XW    = 5518592,  // B*G*D = 16384
  OFF_XS    = 5534976,  // B*D = 4096
  OFF_SW    = 5539072,  // 16 (pad 256)
  OFF_FEAT  = 5539328,  // B*D = 4096
  OFF_KF    = 5543424,  // B*G*D = 16384 [b][g][o]
  OFF_VF    = 5559808,  // B*G*D = 16384
  OFF_AV    = 5576192,  // B*D*G = 16384 [b][d][g]
  OFF_AB    = 5592576,  // B*D = 4096
  OFF_C2    = 5596672,  // B*D = 4096
  OFF_WAV   = 5600768,  // B*D*G = 16384 [b][o][g]
  OFF_WOSUM = 5617152,  // D = 1024
  WS_FLOATS = 5618176   // ~22.5 MB
};

__device__ __forceinline__ float wred_sum(float v) {
#pragma unroll
  for (int o = 32; o > 0; o >>= 1) v += __shfl_xor(v, o, 64);
  return v;
}
__device__ __forceinline__ float wred_max(float v) {
#pragma unroll
  for (int o = 32; o > 0; o >>= 1) v = fmaxf(v, __shfl_xor(v, o, 64));
  return v;
}

// ---- P1: Weff (wave/output), feat, WoSum ----
// blocks [0,192): Weff   [192,208): feat   [208,464): WoSum
__global__ void k_pre1(const float* __restrict__ Woff1, const float* __restrict__ Woff2,
                       const float* __restrict__ x, const float* __restrict__ Wo,
                       float* __restrict__ ws) {
  const int t = threadIdx.x;
  const int lane = t & 63;
  if (blockIdx.x < 192) {                        // Weff[i][kk]
    const int widx = (blockIdx.x * 256 + t) >> 6;   // 0..767
    const int i = widx / 3, kk = widx - 3 * i;
    float a = 0.f;
#pragma unroll
    for (int u = 0; u < 4; ++u) {
      const int cc = lane + 64 * u;
      a += Woff2[cc] * Woff1[(size_t)(cc * DG + i) * KK + kk];
    }
    a = wred_sum(a);
    if (lane == 0) ws[OFF_WEFF + widx] = a;
  } else if (blockIdx.x < 208) {                 // feat[b][c]
    const int gid = (blockIdx.x - 192) * 256 + t;  // 0..4095
    const int b = gid >> 10, c = gid & 1023;
    ws[OFF_FEAT + gid] = 0.5f * (x[((size_t)b * SS + 2047) * DD + c] +
                                 x[((size_t)b * SS + 2048) * DD + c]);
  } else {                                       // WoSum[o]
    const int o = ((blockIdx.x - 208) * 256 + t) >> 6;  // 0..1023
    const float4* wo = (const float4*)(Wo + (size_t)o * DD);
    float v = 0.f;
#pragma unroll
    for (int it = 0; it < 4; ++it) {
      const float4 a = wo[lane + 64 * it];
      v += a.x + a.y + a.z + a.w;
    }
    v = wred_sum(v);
    if (lane == 0) ws[OFF_WOSUM + o] = v;
  }
}

// ---- P2: Weq [0,192) + offc [192] + Kf/Vf [193,1217) ----
__global__ void k_pre2(const float* __restrict__ Wq, const float* __restrict__ bq,
                       const float* __restrict__ Woff2, const float* __restrict__ boff1,
                       const float* __restrict__ Wk, const float* __restrict__ Wv,
                       float* __restrict__ ws) {
  const float* Weff = ws + OFF_WEFF;
  const int t = threadIdx.x;
  const int lane = t & 63;
  if (blockIdx.x < 192) {
    const int j = blockIdx.x >> 4;               // 0..11
    const int c0 = (blockIdx.x & 15) * 64;
    const int g = j / 3, kk = j - 3 * g;
    const int q = t >> 6;
    float a = 0.f;
#pragma unroll 4
    for (int ii = 0; ii < 64; ++ii) {
      const int i = q * 64 + ii;
      a += Weff[i * KK + kk] * Wq[(size_t)(g * DG + i) * DD + c0 + lane];
    }
    __shared__ float red[4][64];
    red[q][lane] = a;
    __syncthreads();
    if (q == 0) {
      const float v = red[0][lane] + red[1][lane] + red[2][lane] + red[3][lane];
      ws[OFF_WEQ + (size_t)j * DD + c0 + lane] = v;
    }
  } else if (blockIdx.x == 192) {                // offc[g] on wave 0
    if (t >= 64) return;
    float beff = 0.f;
#pragma unroll
    for (int u = 0; u < 4; ++u) {
      const int cc = lane + 64 * u;
      beff += Woff2[cc] * boff1[cc];
    }
    beff = wred_sum(beff);
#pragma unroll
    for (int g = 0; g < 4; ++g) {
      float a = 0.f;
#pragma unroll
      for (int u = 0; u < 4; ++u) {
        const int i = lane + 64 * u;
        a += (Weff[i * 3 + 0] + Weff[i * 3 + 1] + Weff[i * 3 + 2]) * bq[g * DG + i];
      }
      a = wred_sum(a);
      if (lane == 0) ws[OFF_OFFC + g] = a + beff;
    }
  } else {                                       // Kf/Vf: wave per (g,o), all 4 b
    const int widx = (blockIdx.x - 193) * 4 + (t >> 6);  // 0..4095
    const int g = widx >> 10, o = widx & 1023;
    const float4 ak = ((const float4*)(Wk + (size_t)o * DD + g * DG))[lane];
    const float4 avv = ((const float4*)(Wv + (size_t)o * DD + g * DG))[lane];
    float kk[4], vv[4];
#pragma unroll
    for (int b = 0; b < 4; ++b) {
      const float4 f = ((const float4*)(ws + OFF_FEAT + (size_t)b * DD + g * DG))[lane];
      kk[b] = ak.x * f.x + ak.y * f.y + ak.z * f.z + ak.w * f.w;
      vv[b] = avv.x * f.x + avv.y * f.y + avv.z * f.z + avv.w * f.w;
    }
#pragma unroll
    for (int b = 0; b < 4; ++b) { kk[b] = wred_sum(kk[b]); vv[b] = wred_sum(vv[b]); }
    if (lane == 0) {
#pragma unroll
      for (int b = 0; b < 4; ++b) {
        ws[OFF_KF + ((size_t)(b * GG + g)) * DD + o] = kk[b];
        ws[OFF_VF + ((size_t)(b * GG + g)) * DD + o] = vv[b];
      }
    }
  }
}

// ---- k_z: zt[b][s][j] = Weq[j,:] . x[b,s,:]  (wave per row, 8 rows/wave) ----
__global__ __launch_bounds__(256, 2) void k_z(const float* __restrict__ x,
                                              const float* __restrict__ weq,
                                              float* __restrict__ zt) {
  const int lane = threadIdx.x & 63;
  const int wave = (blockIdx.x * blockDim.x + threadIdx.x) >> 6;
  const int nwaves = (gridDim.x * blockDim.x) >> 6;
  float4 w[12][4];
#pragma unroll
  for (int j = 0; j < 12; ++j)
#pragma unroll
    for (int it = 0; it < 4; ++it)
      w[j][it] = *(const float4*)(weq + (size_t)j * DD + 4 * (lane + 64 * it));
  for (int row = wave; row < BB * SS; row += nwaves) {
    const float4* xr = (const float4*)(x + (size_t)row * DD);
    float4 xv[4];
#pragma unroll
    for (int it = 0; it < 4; ++it) xv[it] = xr[lane + 64 * it];
    float acc[12];
#pragma unroll
    for (int j = 0; j < 12; ++j) {
      float a = 0.f;
#pragma unroll
      for (int it = 0; it < 4; ++it)
        a += xv[it].x * w[j][it].x + xv[it].y * w[j][it].y +
             xv[it].z * w[j][it].z + xv[it].w * w[j][it].w;
      acc[j] = a;
    }
#pragma unroll
    for (int j = 0; j < 12; ++j) acc[j] = wred_sum(acc[j]);
    if (lane == 0) {
#pragma unroll
      for (int j = 0; j < 12; ++j) zt[(size_t)row * 12 + j] = acc[j];
    }
  }
}

// ---- k_xw: per (b, 16-row chunk): wx from zt (inline) + weighted partial sums ----
__global__ __launch_bounds__(256) void k_xw(const float* __restrict__ x,
                                            float* __restrict__ ws) {
  const int b = blockIdx.x >> 8;
  const int chunk = blockIdx.x & 255;
  const int s0 = chunk * CH;
  const int t = threadIdx.x;
  __shared__ float wxs[4][CH];

  if (t < 64) {                                  // g = t>>4, si = t&15
    const int g = t >> 4, si = t & 15;
    const int s = s0 + si;
    const size_t row = (size_t)b * SS + s;
    const float* zt = ws + OFF_ZT;
    float off = ws[OFF_OFFC + g];
    if (s > 0)      off += zt[(row - 1) * 12 + g * 3 + 0];
    off += zt[row * 12 + g * 3 + 1];
    if (s < SS - 1) off += zt[(row + 1) * 12 + g * 3 + 2];
    off = tanhf(off) * (float)KK;
    const float vg = 2.0f * ((float)s + off) / (float)(SS - 1) - 1.0f;
    float wvv = 1.0f - fabsf(0.5f * vg);
    wvv = fminf(fmaxf(wvv, 0.0f), 1.0f);
    wxs[g][si] = wvv;
    ws[OFF_WX + (size_t)(b * GG + g) * SS + s] = wvv;
  }
  __syncthreads();

  float4 aw[5] = {};
#pragma unroll 4
  for (int si = 0; si < CH; ++si) {
    const int s = s0 + si;
    const float4 f = *(const float4*)(x + (size_t)(b * SS + s) * DD + 4 * t);
    const float w0 = wxs[0][si], w1 = wxs[1][si], w2 = wxs[2][si], w3 = wxs[3][si];
    aw[0].x += f.x * w0; aw[0].y += f.y * w0; aw[0].z += f.z * w0; aw[0].w += f.w * w0;
    aw[1].x += f.x * w1; aw[1].y += f.y * w1; aw[1].z += f.z * w1; aw[1].w += f.w * w1;
    aw[2].x += f.x * w2; aw[2].y += f.y * w2; aw[2].z += f.z * w2; aw[2].w += f.w * w2;
    aw[3].x += f.x * w3; aw[3].y += f.y * w3; aw[3].z += f.z * w3; aw[3].w += f.w * w3;
    aw[4].x += f.x; aw[4].y += f.y; aw[4].z += f.z; aw[4].w += f.w;
  }
#pragma unroll
  for (int slot = 0; slot < 5; ++slot)
    *(float4*)(ws + OFF_XWP + (((size_t)(b * 5 + slot) * NCH + chunk) * DD) + 4 * t) = aw[slot];
}

// ---- k_red: blocks [0,320): Xw/Xs   [320,336): Sw ----
__global__ void k_red(float* __restrict__ ws) {
  const int t = threadIdx.x;
  const int lane = t & 63;
  const int wvid = t >> 6;
  __shared__ float red[4][64];
  if (blockIdx.x < 320) {
    const int rb = blockIdx.x / 80;
    const int rem = blockIdx.x - rb * 80;
    const int slot = rem >> 4;
    const int c = (rem & 15) * 64 + lane;
    const float* base = ws + OFF_XWP + (size_t)(rb * 5 + slot) * NCH * DD;
    float a = 0.f;
#pragma unroll 8
    for (int ii = 0; ii < 64; ++ii)
      a += base[(size_t)(wvid * 64 + ii) * DD + c];
    red[wvid][lane] = a;
    __syncthreads();
    if (wvid == 0) {
      const float v = red[0][lane] + red[1][lane] + red[2][lane] + red[3][lane];
      if (slot < 4) ws[OFF_XW + ((size_t)(rb * GG + slot)) * DD + c] = v;
      else          ws[OFF_XS + (size_t)rb * DD + c] = v;
    }
  } else {                                       // Sw[b*4+g]
    const int w = blockIdx.x - 320;              // 0..15
    const float* wx = ws + OFF_WX + (size_t)w * SS;
    float a = 0.f;
#pragma unroll 4
    for (int it = 0; it < 16; ++it) a += wx[t + 256 * it];
    a = wred_sum(a);
    if (lane == 0) red[0][wvid] = a;
    __syncthreads();
    if (t == 0) ws[OFF_SW + w] = red[0][0] + red[0][1] + red[0][2] + red[0][3];
  }
}

// ---- k_mid: Qw/Qs dots fused with attention. Wave per (b, I=d). ----
__global__ void k_mid(const float* __restrict__ Wq, const float* __restrict__ bq,
                      const float* __restrict__ bk, const float* __restrict__ bv,
                      float* __restrict__ ws) {
  const int t = threadIdx.x;
  const int lane = t & 63;
  const int wave = blockIdx.x * 4 + (t >> 6);    // 0..4095
  const int ab_ = wave >> 10, I = wave & 1023;
  const float4* wq = (const float4*)(Wq + (size_t)I * DD);
  float4 a[4];
#pragma unroll
  for (int it = 0; it < 4; ++it) a[it] = wq[lane + 64 * it];
  float acc[5] = {0.f, 0.f, 0.f, 0.f, 0.f};
#pragma unroll
  for (int g = 0; g < 4; ++g) {
    const float4* xw = (const float4*)(ws + OFF_XW + (size_t)(ab_ * GG + g) * DD);
#pragma unroll
    for (int it = 0; it < 4; ++it) {
      const float4 c = xw[lane + 64 * it];
      acc[g] += a[it].x * c.x + a[it].y * c.y + a[it].z * c.z + a[it].w * c.w;
    }
  }
  const float4* xs = (const float4*)(ws + OFF_XS + (size_t)ab_ * DD);
#pragma unroll
  for (int it = 0; it < 4; ++it) {
    const float4 c = xs[lane + 64 * it];
    acc[4] += a[it].x * c.x + a[it].y * c.y + a[it].z * c.z + a[it].w * c.w;
  }
#pragma unroll
  for (int u = 0; u < 5; ++u) acc[u] = wred_sum(acc[u]);
  const float bqi = bq[I];
  const float q0 = acc[0] + bqi * ws[OFF_SW + ab_ * GG + 0];
  const float q1 = acc[1] + bqi * ws[OFF_SW + ab_ * GG + 1];
  const float q2 = acc[2] + bqi * ws[OFF_SW + ab_ * GG + 2];
  const float q3 = acc[3] + bqi * ws[OFF_SW + ab_ * GG + 3];
  const float qs = acc[4] + (float)SS * bqi;
  // attention row d=I; lane = j within head
  const int J = (I & ~63) | lane;
  const float* Kf = ws + OFF_KF + (size_t)ab_ * GG * DD;
  float sc = q0 * Kf[0 * DD + J] + q1 * Kf[1 * DD + J] +
             q2 * Kf[2 * DD + J] + q3 * Kf[3 * DD + J] + bk[J] * qs;
  sc *= 0.03125f;                                // D^-0.5
  const float m = wred_max(sc);
  const float e = expf(sc - m);
  const float sum = wred_sum(e);
  const float attn = e / sum;
  const float* Vf = ws + OFF_VF + (size_t)ab_ * GG * DD;
#pragma unroll
  for (int g = 0; g < 4; ++g) {
    const float av = wred_sum(attn * Vf[(size_t)g * DD + J]);
    if (lane == 0) ws[OFF_AV + (size_t)wave * 4 + g] = av;
  }
  const float abv = wred_sum(attn * bv[J]);
  if (lane == 0) ws[OFF_AB + wave] = abv;
}

// ---- k_wav: WAV[b,o,g] = sum_d Wo[o,d]*AV[b,d,g]; C2 = sum_d Wo*Ab + bo ----
__global__ void k_wav(const float* __restrict__ Wo, const float* __restrict__ bo,
                      float* __restrict__ ws) {
  const int gid = blockIdx.x * blockDim.x + threadIdx.x;
  const int lane = gid & 63;
  const int w = gid >> 6;                        // w = b*1024 + o
  if (w >= BB * DD) return;
  const int b = w >> 10, o = w & 1023;
  float acc0 = 0, acc1 = 0, acc2 = 0, acc3 = 0, acc4 = 0;
  const float4* wo4 = (const float4*)(Wo + (size_t)o * DD);
  const float* AV = ws + OFF_AV + (size_t)b * DD * 4;
  const float* Ab = ws + OFF_AB + (size_t)b * DD;
#pragma unroll
  for (int it = 0; it < 4; ++it) {
    const int d4 = lane + 64 * it;
    const float4 wv = wo4[d4];
    const float4 a0 = *(const float4*)(AV + (size_t)(4 * d4 + 0) * 4);
    const float4 a1 = *(const float4*)(AV + (size_t)(4 * d4 + 1) * 4);
    const float4 a2 = *(const float4*)(AV + (size_t)(4 * d4 + 2) * 4);
    const float4 a3 = *(const float4*)(AV + (size_t)(4 * d4 + 3) * 4);
    acc0 += wv.x * a0.x + wv.y * a1.x + wv.z * a2.x + wv.w * a3.x;
    acc1 += wv.x * a0.y + wv.y * a1.y + wv.z * a2.y + wv.w * a3.y;
    acc2 += wv.x * a0.z + wv.y * a1.z + wv.z * a2.z + wv.w * a3.z;
    acc3 += wv.x * a0.w + wv.y * a1.w + wv.z * a2.w + wv.w * a3.w;
    const float4 abv = *(const float4*)(Ab + 4 * d4);
    acc4 += wv.x * abv.x + wv.y * abv.y + wv.z * abv.z + wv.w * abv.w;
  }
  acc0 = wred_sum(acc0); acc1 = wred_sum(acc1); acc2 = wred_sum(acc2);
  acc3 = wred_sum(acc3); acc4 = wred_sum(acc4);
  if (lane == 0) {
    float* WAV = ws + OFF_WAV + (size_t)w * 4;
    WAV[0] = acc0; WAV[1] = acc1; WAV[2] = acc2; WAV[3] = acc3;
    ws[OFF_C2 + w] = acc4 + bo[o];
  }
}

// ---- k_out: out[b,s,o] = sum_g wx*WAV + C2 + bias_table[s]*WoSum ----
__global__ __launch_bounds__(256) void k_out(const float* __restrict__ btab,
                                             const float* __restrict__ ws,
                                             float* __restrict__ out) {
  const int b = blockIdx.x >> 8;
  const int ch = blockIdx.x & 255;
  const int t = threadIdx.x;
  const int o0 = 4 * t;
  float4 wav[4];
#pragma unroll
  for (int io = 0; io < 4; ++io)
    wav[io] = *(const float4*)(ws + OFF_WAV + (size_t)(b * DD + o0 + io) * 4);
  const float4 c24 = *(const float4*)(ws + OFF_C2 + (size_t)b * DD + o0);
  const float4 wos4 = *(const float4*)(ws + OFF_WOSUM + o0);
  const float* wx = ws + OFF_WX;
  const int s0 = ch * CH;
#pragma unroll 2
  for (int si = 0; si < CH; ++si) {
    const int s = s0 + si;
    const float w0 = wx[(size_t)(b * GG + 0) * SS + s];
    const float w1 = wx[(size_t)(b * GG + 1) * SS + s];
    const float w2 = wx[(size_t)(b * GG + 2) * SS + s];
    const float w3 = wx[(size_t)(b * GG + 3) * SS + s];
    const float bt = btab[s];
    float4 val;
    val.x = c24.x + bt * wos4.x + w0 * wav[0].x + w1 * wav[0].y + w2 * wav[0].z + w3 * wav[0].w;
    val.y = c24.y + bt * wos4.y + w0 * wav[1].x + w1 * wav[1].y + w2 * wav[1].z + w3 * wav[1].w;
    val.z = c24.z + bt * wos4.z + w0 * wav[2].x + w1 * wav[2].y + w2 * wav[2].z + w3 * wav[2].w;
    val.w = c24.w + bt * wos4.w + w0 * wav[3].x + w1 * wav[3].y + w2 * wav[3].z + w3 * wav[3].w;
    *(float4*)(out + (size_t)(b * SS + s) * DD + o0) = val;
  }
}

extern "C" void kernel_launch(void* const* d_in, const int* in_sizes, int n_in,
                              void* d_out, int out_size, void* d_ws, size_t ws_size,
                              hipStream_t stream) {
  const float* x     = (const float*)d_in[0];
  const float* Wq    = (const float*)d_in[1];
  const float* bq    = (const float*)d_in[2];
  const float* Wk    = (const float*)d_in[3];
  const float* bk    = (const float*)d_in[4];
  const float* Wv    = (const float*)d_in[5];
  const float* bv    = (const float*)d_in[6];
  const float* Wo    = (const float*)d_in[7];
  const float* bo    = (const float*)d_in[8];
  const float* Woff1 = (const float*)d_in[9];
  const float* boff1 = (const float*)d_in[10];
  const float* Woff2 = (const float*)d_in[11];
  const float* btab  = (const float*)d_in[12];
  float* ws  = (float*)d_ws;
  float* out = (float*)d_out;

  k_pre1<<<464, 256, 0, stream>>>(Woff1, Woff2, x, Wo, ws);
  k_pre2<<<1217, 256, 0, stream>>>(Wq, bq, Woff2, boff1, Wk, Wv, ws);
  k_z<<<512, 256, 0, stream>>>(x, ws + OFF_WEQ, ws + OFF_ZT);
  k_xw<<<1024, 256, 0, stream>>>(x, ws);
  k_red<<<336, 256, 0, stream>>>(ws);
  k_mid<<<1024, 256, 0, stream>>>(Wq, bq, bk, bv, ws);
  k_wav<<<1024, 256, 0, stream>>>(Wo, bo, ws);
  k_out<<<1024, 256, 0, stream>>>(btab, ws, out);
}